// Round 4
// baseline (274.411 us; speedup 1.0000x reference)
//
#include <hip/hip_runtime.h>
#include <hip/hip_bf16.h>
#include <stdint.h>

// Shapes (fixed): B=4, S=2048, D_MODEL=D_K=D_V=1024
#define SEQ   2048
#define DM    1024
#define NBAT  4

typedef __attribute__((ext_vector_type(8))) short  short8;   // 8 bf16 = 4 VGPRs (MFMA A/B frag)
typedef __attribute__((ext_vector_type(4))) float  floatx4;  // MFMA C/D frag

__device__ __forceinline__ unsigned short f2b(float f) {
    __hip_bfloat16 h = __float2bfloat16(f);
    unsigned short r;
    __builtin_memcpy(&r, &h, 2);
    return r;
}

__device__ __forceinline__ ushort4 pack4(float a, float b, float c, float d) {
    ushort4 u; u.x = f2b(a); u.y = f2b(b); u.z = f2b(c); u.w = f2b(d); return u;
}

// async global->LDS, 16B per lane. dst must be wave-uniform base (lane*16 added by HW).
__device__ __forceinline__ void gload16(const void* g, void* s) {
    __builtin_amdgcn_global_load_lds(
        (const __attribute__((address_space(1))) unsigned int*)(uintptr_t)g,
        (__attribute__((address_space(3))) unsigned int*)(uintptr_t)s,
        16, 0, 0);
}

// One fused prep dispatch: x cast (blocks 0..8191), Wq/Wk/Wv cast into contiguous
// wall[3*DM,DM] (blocks 8192..11263), rowsum zero (blocks 11264..11295).
__global__ void prep(const float4* __restrict__ x,
                     const float4* __restrict__ w0, const float4* __restrict__ w1,
                     const float4* __restrict__ w2,
                     ushort4* __restrict__ xb, ushort4* __restrict__ wall,
                     float* __restrict__ rsum)
{
    const int b = blockIdx.x;
    const int t = threadIdx.x;
    if (b < 8192) {                       // x: 8192*1024 elems = 2097152 float4
        const int i = b * 256 + t;
        float4 f = x[i];
        xb[i] = pack4(f.x, f.y, f.z, f.w);
    } else if (b < 11264) {               // weights: 3 x 262144 float4
        const int idx  = b - 8192;
        const int wsel = idx >> 10;
        const int i    = (idx & 1023) * 256 + t;
        const float4* src = (wsel == 0) ? w0 : (wsel == 1) ? w1 : w2;
        float4 f = src[i];
        wall[(size_t)wsel * 262144 + i] = pack4(f.x, f.y, f.z, f.w);
    } else {                              // rowsum: 8192 floats = 32 blocks
        rsum[(b - 11264) * 256 + t] = 0.f;
    }
}

// ---------------------------------------------------------------------------
// Shared structure (measured R3: 0 bank conflicts, 23.5 us per 16-K-tile
// block): BM=256, BN=128, BK=64, 8 waves (4Mx2N, 64x64 each), counted-vmcnt
// pipeline, 3-slot LDS ring (144 KB), stage 2 tiles ahead.
// LDS chunk = [128 rows][64 k] bf16 = 16 KB, R0-proven layout: row stride
// 128 B, 16B piece slot s of row R holds global piece s^(R&7); frag reads
// use slot (kk*4+q)^(r&7). Per K-tile: 2 phases (kk=0/1), each
// {8 ds_read_b128, chunk stages of tile t+2, barrier, lgkmcnt(0), setprio(1),
// 16 MFMA, setprio(0), barrier}; vmcnt(6) once per tile (phase B, never 0).
// ---------------------------------------------------------------------------
#define SLOTS 24576   // shorts per ring slot: A c0 [0,8192) A c1 [8192,16384) B [16384,24576)

__global__ __launch_bounds__(512, 2) void qkv_gemm(
    const unsigned short* __restrict__ A, const unsigned short* __restrict__ Bm,
    unsigned short* __restrict__ Qo, unsigned short* __restrict__ Ko,
    unsigned short* __restrict__ Vto, float qscale)
{
    __shared__ __align__(16) unsigned short lds[3 * SLOTS];   // 144 KB

    // XCD-aware swizzle: 768 blocks = 8 XCDs * 96, bijective, mt-major per XCD.
    const int bid = blockIdx.x;
    const int wg  = (bid & 7) * 96 + (bid >> 3);
    const int mt  = wg / 24, nt = wg - mt * 24;
    const int m0  = mt * 256, n0 = nt * 128;

    const int t    = threadIdx.x;
    const int w    = t >> 6;          // wave 0..7
    const int lane = t & 63;
    const int wr   = w >> 1, wc = w & 1;
    const int r    = lane & 15, q = lane >> 4;

    // staging (R0-proven): thread covers rows w*16 + {0,8} + (lane>>3) of a chunk;
    // LDS slot = lane&7 (linear dest), global piece = (lane&7)^(lane>>3).
    const int srow = lane >> 3;                       // 0..7
    const int scol = ((lane & 7) ^ srow) << 3;        // elem offset within 64-col row

    // fragment-read constants: base + kk-slot offsets
    const int aoff = (wr >> 1) * 8192 + ((wr & 1) * 64 + r) * 64;   // A chunk + row base
    const int boff = 16384 + (wc * 64 + r) * 64;                    // B chunk + row base
    const int sk0  = ((0 + q) ^ (r & 7)) * 8;                       // kk=0 slot
    const int sk1  = ((4 + q) ^ (r & 7)) * 8;                       // kk=1 slot

    floatx4 acc[4][4];
#pragma unroll
    for (int i = 0; i < 4; i++)
#pragma unroll
        for (int j = 0; j < 4; j++)
            acc[i][j] = (floatx4){0.f, 0.f, 0.f, 0.f};

#define STGA(KB, SL) do { \
    gload16(A + (((size_t)(m0 +       w * 16 + srow)) << 10) + (KB) + scol, &lds[(SL) +         w * 1024]); \
    gload16(A + (((size_t)(m0 +   8 + w * 16 + srow)) << 10) + (KB) + scol, &lds[(SL) +         w * 1024 + 512]); \
    gload16(A + (((size_t)(m0 + 128 + w * 16 + srow)) << 10) + (KB) + scol, &lds[(SL) + 8192 +  w * 1024]); \
    gload16(A + (((size_t)(m0 + 136 + w * 16 + srow)) << 10) + (KB) + scol, &lds[(SL) + 8192 +  w * 1024 + 512]); \
  } while (0)
#define STGB(KB, SL) do { \
    gload16(Bm + (((size_t)(n0 +      w * 16 + srow)) << 10) + (KB) + scol, &lds[(SL) + 16384 + w * 1024]); \
    gload16(Bm + (((size_t)(n0 +  8 + w * 16 + srow)) << 10) + (KB) + scol, &lds[(SL) + 16384 + w * 1024 + 512]); \
  } while (0)

#define MFMA16() do { \
    acc[0][0] = __builtin_amdgcn_mfma_f32_16x16x32_bf16(af0, bf0, acc[0][0], 0, 0, 0); \
    acc[0][1] = __builtin_amdgcn_mfma_f32_16x16x32_bf16(af0, bf1, acc[0][1], 0, 0, 0); \
    acc[0][2] = __builtin_amdgcn_mfma_f32_16x16x32_bf16(af0, bf2, acc[0][2], 0, 0, 0); \
    acc[0][3] = __builtin_amdgcn_mfma_f32_16x16x32_bf16(af0, bf3, acc[0][3], 0, 0, 0); \
    acc[1][0] = __builtin_amdgcn_mfma_f32_16x16x32_bf16(af1, bf0, acc[1][0], 0, 0, 0); \
    acc[1][1] = __builtin_amdgcn_mfma_f32_16x16x32_bf16(af1, bf1, acc[1][1], 0, 0, 0); \
    acc[1][2] = __builtin_amdgcn_mfma_f32_16x16x32_bf16(af1, bf2, acc[1][2], 0, 0, 0); \
    acc[1][3] = __builtin_amdgcn_mfma_f32_16x16x32_bf16(af1, bf3, acc[1][3], 0, 0, 0); \
    acc[2][0] = __builtin_amdgcn_mfma_f32_16x16x32_bf16(af2, bf0, acc[2][0], 0, 0, 0); \
    acc[2][1] = __builtin_amdgcn_mfma_f32_16x16x32_bf16(af2, bf1, acc[2][1], 0, 0, 0); \
    acc[2][2] = __builtin_amdgcn_mfma_f32_16x16x32_bf16(af2, bf2, acc[2][2], 0, 0, 0); \
    acc[2][3] = __builtin_amdgcn_mfma_f32_16x16x32_bf16(af2, bf3, acc[2][3], 0, 0, 0); \
    acc[3][0] = __builtin_amdgcn_mfma_f32_16x16x32_bf16(af3, bf0, acc[3][0], 0, 0, 0); \
    acc[3][1] = __builtin_amdgcn_mfma_f32_16x16x32_bf16(af3, bf1, acc[3][1], 0, 0, 0); \
    acc[3][2] = __builtin_amdgcn_mfma_f32_16x16x32_bf16(af3, bf2, acc[3][2], 0, 0, 0); \
    acc[3][3] = __builtin_amdgcn_mfma_f32_16x16x32_bf16(af3, bf3, acc[3][3], 0, 0, 0); \
  } while (0)

    // prologue: stage tiles 0 and 1 (12 loads); vmcnt(6) -> tile 0's 6 chunks landed
    STGA(0, 0);
    STGB(0, 0);
    STGA(64, SLOTS);
    STGB(64, SLOTS);
    asm volatile("s_waitcnt vmcnt(6)" ::: "memory");
    __builtin_amdgcn_s_barrier();

    short8 af0, af1, af2, af3, bf0, bf1, bf2, bf3;

    for (int tt = 0; tt < 16; ++tt) {
        const int sl  = (tt % 3) * SLOTS;
        const int nsl = ((tt + 2) % 3) * SLOTS;
        const int nkb = (tt + 2 < 16) ? (tt + 2) * 64 : 0;   // wrap: harmless prefetch

        // ---- phase A (kk=0) ----
        {
            const int aB = sl + aoff + sk0;
            const int bB = sl + boff + sk0;
            af0 = *(const short8*)&lds[aB +    0];
            af1 = *(const short8*)&lds[aB + 1024];
            af2 = *(const short8*)&lds[aB + 2048];
            af3 = *(const short8*)&lds[aB + 3072];
            bf0 = *(const short8*)&lds[bB +    0];
            bf1 = *(const short8*)&lds[bB + 1024];
            bf2 = *(const short8*)&lds[bB + 2048];
            bf3 = *(const short8*)&lds[bB + 3072];
            STGA(nkb, nsl);
            __builtin_amdgcn_s_barrier();
            asm volatile("s_waitcnt lgkmcnt(0)" ::: "memory");
            __builtin_amdgcn_s_setprio(1);
            MFMA16();
            __builtin_amdgcn_s_setprio(0);
            __builtin_amdgcn_s_barrier();
        }
        // ---- phase B (kk=1) ----
        {
            const int aB = sl + aoff + sk1;
            const int bB = sl + boff + sk1;
            af0 = *(const short8*)&lds[aB +    0];
            af1 = *(const short8*)&lds[aB + 1024];
            af2 = *(const short8*)&lds[aB + 2048];
            af3 = *(const short8*)&lds[aB + 3072];
            bf0 = *(const short8*)&lds[bB +    0];
            bf1 = *(const short8*)&lds[bB + 1024];
            bf2 = *(const short8*)&lds[bB + 2048];
            bf3 = *(const short8*)&lds[bB + 3072];
            STGB(nkb, nsl);
            asm volatile("s_waitcnt vmcnt(6)" ::: "memory");
            __builtin_amdgcn_s_barrier();
            asm volatile("s_waitcnt lgkmcnt(0)" ::: "memory");
            __builtin_amdgcn_s_setprio(1);
            MFMA16();
            __builtin_amdgcn_s_setprio(0);
            __builtin_amdgcn_s_barrier();
        }
    }
#undef STGA
#undef STGB
#undef MFMA16

    // epilogue (unswapped): row = m0 + wr*64 + i*16 + q*4 + rr, col = n0 + wc*64 + j*16 + r
    const int gmb = m0 + wr * 64 + q * 4;
    const int gnb = n0 + wc * 64 + r;
    if (nt < 8) {
#pragma unroll
        for (int i = 0; i < 4; i++) {
            const int gm = gmb + i * 16;
#pragma unroll
            for (int j = 0; j < 4; j++) {
                const int gn = gnb + j * 16;
#pragma unroll
                for (int rr = 0; rr < 4; rr++)
                    Qo[(size_t)(gm + rr) * 1024 + gn] = f2b(acc[i][j][rr] * qscale);
            }
        }
    } else if (nt < 16) {
#pragma unroll
        for (int i = 0; i < 4; i++) {
            const int gm = gmb + i * 16;
#pragma unroll
            for (int j = 0; j < 4; j++) {
                const int gn = gnb + j * 16;
#pragma unroll
                for (int rr = 0; rr < 4; rr++)
                    Ko[(size_t)(gm + rr) * 1024 + (gn - 1024)] = f2b(acc[i][j][rr]);
            }
        }
    } else {
#pragma unroll
        for (int i = 0; i < 4; i++) {
            const int gm = gmb + i * 16;
            const int b  = gm >> 11;
            const int s  = gm & 2047;          // 4 consecutive tokens via rr
#pragma unroll
            for (int j = 0; j < 4; j++) {
                const int v = gnb + j * 16 - 2048;
                *(ushort4*)&Vto[((size_t)(b * 1024 + v)) * 2048 + s] =
                    pack4(acc[i][j][0], acc[i][j][1], acc[i][j][2], acc[i][j][3]);
            }
        }
    }
}

// ---------------------------------------------------------------------------
// Attention GEMMs, R4: clone of the measured qkv structure (BM=256, BN=128,
// BK=64, 8 waves 4Mx2N, ring-3, counted vmcnt(6), R0 LDS layout, setprio)
// replacing the old m97-style attn64 (full drain per K-tile, wave tile 32x64).
// MFMA operand order SWAPPED (mfma(bf,af)) -> per-thread layout
// row gm = m0 + wr*64 + i*16 + r, col gn = n0 + wc*64 + j*16 + q*4 + rr
// -> 4 consecutive cols per acc: ushort4/float4 stores, 2-shfl rowsum reduce.
// MODE 0 (scores): lower-tri 256x128 tiles, f = ti(ti+1)+tj, tj in [0,2ti+2);
//   E = exp(s) causal (bf16) + rowsum atomics; kEnd = 1024.
// MODE 1 (PV): C = E*Vt^T / rowsum; kEnd = m0+256, heavy m-tiles first.
// ---------------------------------------------------------------------------
template<int MODE>
__global__ __launch_bounds__(512, 2) void attn256(
    const unsigned short* __restrict__ Ag, const unsigned short* __restrict__ Bg,
    void* __restrict__ Cv, float* __restrict__ rowsum)
{
    __shared__ __align__(16) unsigned short lds[3 * SLOTS];   // 144 KB

    const int z = blockIdx.z;
    int m0, n0;
    if (MODE == 0) {
        // f = ti*(ti+1) + tj, tj in [0, 2ti+2)  (lower-tri tiles of 8 x 16 grid)
        const int f = blockIdx.x;
        int ti = (int)((sqrtf(4.f * f + 1.f) - 1.f) * 0.5f);
        while ((ti + 1) * (ti + 2) <= f) ti++;
        while (ti * (ti + 1) > f) ti--;
        const int tj = f - ti * (ti + 1);
        m0 = ti * 256;
        n0 = tj * 128;
    } else {
        m0 = (int)(gridDim.y - 1 - blockIdx.y) * 256;   // heavy (large kEnd) first
        n0 = blockIdx.x * 128;
    }

    const size_t LDA = (MODE == 0) ? DM : SEQ;
    const size_t LDB = (MODE == 0) ? DM : SEQ;
    const unsigned short* A  = Ag + (size_t)z * ((MODE == 0) ? SEQ * DM : SEQ * SEQ);
    const unsigned short* Bm = Bg + (size_t)z * ((MODE == 0) ? SEQ * DM : DM * SEQ);
    const int NT = ((MODE == 0) ? DM : (m0 + 256)) / 64;   // K-tiles (>= 4)

    const int t    = threadIdx.x;
    const int w    = t >> 6;
    const int lane = t & 63;
    const int wr   = w >> 1, wc = w & 1;
    const int r    = lane & 15, q = lane >> 4;

    const int srow = lane >> 3;
    const int scol = ((lane & 7) ^ srow) << 3;

    const int aoff = (wr >> 1) * 8192 + ((wr & 1) * 64 + r) * 64;
    const int boff = 16384 + (wc * 64 + r) * 64;
    const int sk0  = ((0 + q) ^ (r & 7)) * 8;
    const int sk1  = ((4 + q) ^ (r & 7)) * 8;

    floatx4 acc[4][4];
#pragma unroll
    for (int i = 0; i < 4; i++)
#pragma unroll
        for (int j = 0; j < 4; j++)
            acc[i][j] = (floatx4){0.f, 0.f, 0.f, 0.f};

#define ASTG(KB, SL) do { \
    gload16(A + (size_t)(m0 +       w * 16 + srow) * LDA + (KB) + scol, &lds[(SL) +         w * 1024]); \
    gload16(A + (size_t)(m0 +   8 + w * 16 + srow) * LDA + (KB) + scol, &lds[(SL) +         w * 1024 + 512]); \
    gload16(A + (size_t)(m0 + 128 + w * 16 + srow) * LDA + (KB) + scol, &lds[(SL) + 8192 +  w * 1024]); \
    gload16(A + (size_t)(m0 + 136 + w * 16 + srow) * LDA + (KB) + scol, &lds[(SL) + 8192 +  w * 1024 + 512]); \
  } while (0)
#define BSTG(KB, SL) do { \
    gload16(Bm + (size_t)(n0 +      w * 16 + srow) * LDB + (KB) + scol, &lds[(SL) + 16384 + w * 1024]); \
    gload16(Bm + (size_t)(n0 +  8 + w * 16 + srow) * LDB + (KB) + scol, &lds[(SL) + 16384 + w * 1024 + 512]); \
  } while (0)

#define MFMA16S() do { \
    acc[0][0] = __builtin_amdgcn_mfma_f32_16x16x32_bf16(bf0, af0, acc[0][0], 0, 0, 0); \
    acc[0][1] = __builtin_amdgcn_mfma_f32_16x16x32_bf16(bf1, af0, acc[0][1], 0, 0, 0); \
    acc[0][2] = __builtin_amdgcn_mfma_f32_16x16x32_bf16(bf2, af0, acc[0][2], 0, 0, 0); \
    acc[0][3] = __builtin_amdgcn_mfma_f32_16x16x32_bf16(bf3, af0, acc[0][3], 0, 0, 0); \
    acc[1][0] = __builtin_amdgcn_mfma_f32_16x16x32_bf16(bf0, af1, acc[1][0], 0, 0, 0); \
    acc[1][1] = __builtin_amdgcn_mfma_f32_16x16x32_bf16(bf1, af1, acc[1][1], 0, 0, 0); \
    acc[1][2] = __builtin_amdgcn_mfma_f32_16x16x32_bf16(bf2, af1, acc[1][2], 0, 0, 0); \
    acc[1][3] = __builtin_amdgcn_mfma_f32_16x16x32_bf16(bf3, af1, acc[1][3], 0, 0, 0); \
    acc[2][0] = __builtin_amdgcn_mfma_f32_16x16x32_bf16(bf0, af2, acc[2][0], 0, 0, 0); \
    acc[2][1] = __builtin_amdgcn_mfma_f32_16x16x32_bf16(bf1, af2, acc[2][1], 0, 0, 0); \
    acc[2][2] = __builtin_amdgcn_mfma_f32_16x16x32_bf16(bf2, af2, acc[2][2], 0, 0, 0); \
    acc[2][3] = __builtin_amdgcn_mfma_f32_16x16x32_bf16(bf3, af2, acc[2][3], 0, 0, 0); \
    acc[3][0] = __builtin_amdgcn_mfma_f32_16x16x32_bf16(bf0, af3, acc[3][0], 0, 0, 0); \
    acc[3][1] = __builtin_amdgcn_mfma_f32_16x16x32_bf16(bf1, af3, acc[3][1], 0, 0, 0); \
    acc[3][2] = __builtin_amdgcn_mfma_f32_16x16x32_bf16(bf2, af3, acc[3][2], 0, 0, 0); \
    acc[3][3] = __builtin_amdgcn_mfma_f32_16x16x32_bf16(bf3, af3, acc[3][3], 0, 0, 0); \
  } while (0)

    ASTG(0, 0);
    BSTG(0, 0);
    ASTG(64, SLOTS);
    BSTG(64, SLOTS);
    asm volatile("s_waitcnt vmcnt(6)" ::: "memory");
    __builtin_amdgcn_s_barrier();

    short8 af0, af1, af2, af3, bf0, bf1, bf2, bf3;

    for (int tt = 0; tt < NT; ++tt) {
        const int sl  = (tt % 3) * SLOTS;
        const int nsl = ((tt + 2) % 3) * SLOTS;
        const int nkb = (tt + 2 < NT) ? (tt + 2) * 64 : 0;   // wrap: harmless prefetch

        // ---- phase A (kk=0) ----
        {
            const int aB = sl + aoff + sk0;
            const int bB = sl + boff + sk0;
            af0 = *(const short8*)&lds[aB +    0];
            af1 = *(const short8*)&lds[aB + 1024];
            af2 = *(const short8*)&lds[aB + 2048];
            af3 = *(const short8*)&lds[aB + 3072];
            bf0 = *(const short8*)&lds[bB +    0];
            bf1 = *(const short8*)&lds[bB + 1024];
            bf2 = *(const short8*)&lds[bB + 2048];
            bf3 = *(const short8*)&lds[bB + 3072];
            ASTG(nkb, nsl);
            __builtin_amdgcn_s_barrier();
            asm volatile("s_waitcnt lgkmcnt(0)" ::: "memory");
            __builtin_amdgcn_s_setprio(1);
            MFMA16S();
            __builtin_amdgcn_s_setprio(0);
            __builtin_amdgcn_s_barrier();
        }
        // ---- phase B (kk=1) ----
        {
            const int aB = sl + aoff + sk1;
            const int bB = sl + boff + sk1;
            af0 = *(const short8*)&lds[aB +    0];
            af1 = *(const short8*)&lds[aB + 1024];
            af2 = *(const short8*)&lds[aB + 2048];
            af3 = *(const short8*)&lds[aB + 3072];
            bf0 = *(const short8*)&lds[bB +    0];
            bf1 = *(const short8*)&lds[bB + 1024];
            bf2 = *(const short8*)&lds[bB + 2048];
            bf3 = *(const short8*)&lds[bB + 3072];
            BSTG(nkb, nsl);
            asm volatile("s_waitcnt vmcnt(6)" ::: "memory");
            __builtin_amdgcn_s_barrier();
            asm volatile("s_waitcnt lgkmcnt(0)" ::: "memory");
            __builtin_amdgcn_s_setprio(1);
            MFMA16S();
            __builtin_amdgcn_s_setprio(0);
            __builtin_amdgcn_s_barrier();
        }
    }
#undef ASTG
#undef BSTG
#undef MFMA16S

    // swapped epilogue: row gm = m0 + wr*64 + i*16 + r, col gn = n0 + wc*64 + j*16 + q*4 + rr
    const int gmb = m0 + wr * 64 + r;
    const int gnb = n0 + wc * 64 + q * 4;
    if (MODE == 0) {
        unsigned short* E = (unsigned short*)Cv + (size_t)z * SEQ * SEQ;
        float* rs = rowsum + (size_t)z * SEQ;
#pragma unroll
        for (int i = 0; i < 4; i++) {
            const int gm = gmb + i * 16;
            float part = 0.f;
#pragma unroll
            for (int j = 0; j < 4; j++) {
                const int gn = gnb + j * 16;
                float e0 = (gn + 0 <= gm) ? __expf(acc[i][j][0]) : 0.f;
                float e1 = (gn + 1 <= gm) ? __expf(acc[i][j][1]) : 0.f;
                float e2 = (gn + 2 <= gm) ? __expf(acc[i][j][2]) : 0.f;
                float e3 = (gn + 3 <= gm) ? __expf(acc[i][j][3]) : 0.f;
                part += (e0 + e1) + (e2 + e3);
                *(ushort4*)&E[(size_t)gm * SEQ + gn] = pack4(e0, e1, e2, e3);
            }
            // the 4 lanes sharing row gm differ only in q (lane bits 4-5)
            part += __shfl_xor(part, 16, 64);
            part += __shfl_xor(part, 32, 64);
            if (q == 0) atomicAdd(&rs[gm], part);
        }
    } else {
        float* C = (float*)Cv + (size_t)z * SEQ * DM;
        const float* rs = rowsum + (size_t)z * SEQ;
#pragma unroll
        for (int i = 0; i < 4; i++) {
            const int gm = gmb + i * 16;
            const float inv = 1.0f / rs[gm];
#pragma unroll
            for (int j = 0; j < 4; j++) {
                const int gn = gnb + j * 16;
                float4 o;
                o.x = acc[i][j][0] * inv;
                o.y = acc[i][j][1] * inv;
                o.z = acc[i][j][2] * inv;
                o.w = acc[i][j][3] * inv;
                *(float4*)&C[(size_t)gm * DM + gn] = o;
            }
        }
    }
}

extern "C" void kernel_launch(void* const* d_in, const int* in_sizes, int n_in,
                              void* d_out, int out_size, void* d_ws, size_t ws_size,
                              hipStream_t stream) {
    (void)in_sizes; (void)n_in; (void)out_size; (void)ws_size;
    const float* x  = (const float*)d_in[0];
    // d_in[1] = mask (causal; implicit — unused)
    const float* Wq = (const float*)d_in[2];
    const float* Wk = (const float*)d_in[3];
    const float* Wv = (const float*)d_in[4];

    char* base = (char*)d_ws;
    size_t off = 0;
    auto alloc = [&](size_t n) { char* p = base + off; off += (n + 255) & ~(size_t)255; return p; };

    unsigned short* xb   = (unsigned short*)alloc((size_t)NBAT * SEQ * DM * 2);  // 16.8 MB
    unsigned short* wall = (unsigned short*)alloc((size_t)3 * DM * DM * 2);      // 6.3 MB
    unsigned short* Qb   = (unsigned short*)alloc((size_t)NBAT * SEQ * DM * 2);  // scaled 1/32
    unsigned short* Kb   = (unsigned short*)alloc((size_t)NBAT * SEQ * DM * 2);
    unsigned short* Vtb  = (unsigned short*)alloc((size_t)NBAT * DM * SEQ * 2);  // [b][v][s]
    unsigned short* E    = (unsigned short*)alloc((size_t)NBAT * SEQ * SEQ * 2); // 33.5 MB
    float*          rsum = (float*)alloc((size_t)NBAT * SEQ * 4);

    // 1) fused prep: x cast + weight casts + rowsum zero (one dispatch, 11296 blocks)
    prep<<<dim3(11296), dim3(256), 0, stream>>>(
        (const float4*)x, (const float4*)Wq, (const float4*)Wk, (const float4*)Wv,
        (ushort4*)xb, (ushort4*)wall, rsum);

    // 2) fused QKV projection: 256x128 tiles, BK=64, 3-slot ring, counted vmcnt;
    //    32x24 = 768 blocks = 3 exact rounds; 1/sqrt(d_k) folded into Q epilogue.
    qkv_gemm<<<dim3(768), dim3(512), 0, stream>>>(
        xb, wall, Qb, Kb, Vtb, 0.03125f);

    // 3) E = exp(Q K^T) causal (bf16) + rowsum; 72 tri-tiles/batch x 4 = 288 blocks
    attn256<0><<<dim3(72, 1, NBAT), dim3(512), 0, stream>>>(Qb, Kb, E, rsum);

    // 4) out = (E Vt^T)/rowsum; 8x8x4 = 256 blocks, heavy m-tiles first
    attn256<1><<<dim3(DM / 128, SEQ / 256, NBAT), dim3(512), 0, stream>>>(E, Vtb, d_out, rsum);
}

// Round 5
// 260.468 us; speedup vs baseline: 1.0535x; 1.0535x over previous
//
#include <hip/hip_runtime.h>
#include <hip/hip_bf16.h>
#include <stdint.h>

// Shapes (fixed): B=4, S=2048, D_MODEL=D_K=D_V=1024
#define SEQ   2048
#define DM    1024
#define NBAT  4

typedef __attribute__((ext_vector_type(8))) short  short8;   // 8 bf16 = 4 VGPRs (MFMA A/B frag)
typedef __attribute__((ext_vector_type(4))) float  floatx4;  // MFMA C/D frag

__device__ __forceinline__ unsigned short f2b(float f) {
    __hip_bfloat16 h = __float2bfloat16(f);
    unsigned short r;
    __builtin_memcpy(&r, &h, 2);
    return r;
}

__device__ __forceinline__ ushort4 pack4(float a, float b, float c, float d) {
    ushort4 u; u.x = f2b(a); u.y = f2b(b); u.z = f2b(c); u.w = f2b(d); return u;
}

// async global->LDS, 16B per lane. dst must be wave-uniform base (lane*16 added by HW).
__device__ __forceinline__ void gload16(const void* g, void* s) {
    __builtin_amdgcn_global_load_lds(
        (const __attribute__((address_space(1))) unsigned int*)(uintptr_t)g,
        (__attribute__((address_space(3))) unsigned int*)(uintptr_t)s,
        16, 0, 0);
}

// One fused prep dispatch: x cast (blocks 0..8191), Wq/Wk/Wv cast into contiguous
// wall[3*DM,DM] (blocks 8192..11263), rowsum zero (blocks 11264..11295).
__global__ void prep(const float4* __restrict__ x,
                     const float4* __restrict__ w0, const float4* __restrict__ w1,
                     const float4* __restrict__ w2,
                     ushort4* __restrict__ xb, ushort4* __restrict__ wall,
                     float* __restrict__ rsum)
{
    const int b = blockIdx.x;
    const int t = threadIdx.x;
    if (b < 8192) {                       // x: 8192*1024 elems = 2097152 float4
        const int i = b * 256 + t;
        float4 f = x[i];
        xb[i] = pack4(f.x, f.y, f.z, f.w);
    } else if (b < 11264) {               // weights: 3 x 262144 float4
        const int idx  = b - 8192;
        const int wsel = idx >> 10;
        const int i    = (idx & 1023) * 256 + t;
        const float4* src = (wsel == 0) ? w0 : (wsel == 1) ? w1 : w2;
        float4 f = src[i];
        wall[(size_t)wsel * 262144 + i] = pack4(f.x, f.y, f.z, f.w);
    } else {                              // rowsum: 8192 floats = 32 blocks
        rsum[(b - 11264) * 256 + t] = 0.f;
    }
}

// ---------------------------------------------------------------------------
// Shared structure: BM=256, BN=128, BK=64, 8 waves (4Mx2N, 64x64 each),
// counted-vmcnt pipeline, 3-slot LDS ring (144 KB), stage 2 tiles ahead.
// LDS chunk = [128 rows][64 k] bf16 = 16 KB, R0-proven zero-conflict layout:
// row stride 128 B, 16B piece slot s of row R holds global piece s^(R&7);
// frag reads use slot (kk*4+q)^(r&7).
// R5 sync restructure (R4 lesson: 4 barriers + 2 full lgkmcnt drains per
// K-tile left MfmaUtil at 30%, half of all cycles idle): ONE barrier per
// K-tile, no explicit lgkmcnt — per K-tile {16 ds_read (both kk), stage 6
// gloads of tile t+2, vmcnt(6), barrier, setprio(1), 32 MFMA, setprio(0)}.
// Hazard trace: reads(t) vs STG(t+3) separated by barrier(t); slot-t data
// guaranteed by vmcnt(6)+barrier at iter t-1 (t's 6 loads are older than
// the newest 6). Compiler emits fine-grained lgkmcnt(N) for ds_read->MFMA.
// ---------------------------------------------------------------------------
#define SLOTS 24576   // shorts per ring slot: A c0 [0,8192) A c1 [8192,16384) B [16384,24576)

__global__ __launch_bounds__(512, 2) void qkv_gemm(
    const unsigned short* __restrict__ A, const unsigned short* __restrict__ Bm,
    unsigned short* __restrict__ Qo, unsigned short* __restrict__ Ko,
    unsigned short* __restrict__ Vto, float qscale)
{
    __shared__ __align__(16) unsigned short lds[3 * SLOTS];   // 144 KB

    // XCD-aware swizzle: 768 blocks = 8 XCDs * 96, bijective, mt-major per XCD.
    const int bid = blockIdx.x;
    const int wg  = (bid & 7) * 96 + (bid >> 3);
    const int mt  = wg / 24, nt = wg - mt * 24;
    const int m0  = mt * 256, n0 = nt * 128;

    const int t    = threadIdx.x;
    const int w    = t >> 6;          // wave 0..7
    const int lane = t & 63;
    const int wr   = w >> 1, wc = w & 1;
    const int r    = lane & 15, q = lane >> 4;

    // staging (R0-proven): thread covers rows w*16 + {0,8} + (lane>>3) of a chunk;
    // LDS slot = lane&7 (linear dest), global piece = (lane&7)^(lane>>3).
    const int srow = lane >> 3;                       // 0..7
    const int scol = ((lane & 7) ^ srow) << 3;        // elem offset within 64-col row

    // fragment-read constants: base + kk-slot offsets
    const int aoff = (wr >> 1) * 8192 + ((wr & 1) * 64 + r) * 64;   // A chunk + row base
    const int boff = 16384 + (wc * 64 + r) * 64;                    // B chunk + row base
    const int sk0  = ((0 + q) ^ (r & 7)) * 8;                       // kk=0 slot
    const int sk1  = ((4 + q) ^ (r & 7)) * 8;                       // kk=1 slot

    floatx4 acc[4][4];
#pragma unroll
    for (int i = 0; i < 4; i++)
#pragma unroll
        for (int j = 0; j < 4; j++)
            acc[i][j] = (floatx4){0.f, 0.f, 0.f, 0.f};

#define STGA(KB, SL) do { \
    gload16(A + (((size_t)(m0 +       w * 16 + srow)) << 10) + (KB) + scol, &lds[(SL) +         w * 1024]); \
    gload16(A + (((size_t)(m0 +   8 + w * 16 + srow)) << 10) + (KB) + scol, &lds[(SL) +         w * 1024 + 512]); \
    gload16(A + (((size_t)(m0 + 128 + w * 16 + srow)) << 10) + (KB) + scol, &lds[(SL) + 8192 +  w * 1024]); \
    gload16(A + (((size_t)(m0 + 136 + w * 16 + srow)) << 10) + (KB) + scol, &lds[(SL) + 8192 +  w * 1024 + 512]); \
  } while (0)
#define STGB(KB, SL) do { \
    gload16(Bm + (((size_t)(n0 +      w * 16 + srow)) << 10) + (KB) + scol, &lds[(SL) + 16384 + w * 1024]); \
    gload16(Bm + (((size_t)(n0 +  8 + w * 16 + srow)) << 10) + (KB) + scol, &lds[(SL) + 16384 + w * 1024 + 512]); \
  } while (0)

    // prologue: stage tiles 0 and 1 (12 loads); vmcnt(6) -> tile 0's 6 chunks landed
    STGA(0, 0);
    STGB(0, 0);
    STGA(64, SLOTS);
    STGB(64, SLOTS);
    asm volatile("s_waitcnt vmcnt(6)" ::: "memory");
    __builtin_amdgcn_s_barrier();

    for (int tt = 0; tt < 16; ++tt) {
        const int sl  = (tt % 3) * SLOTS;
        const int nsl = ((tt + 2) % 3) * SLOTS;
        const int nkb = (tt + 2 < 16) ? (tt + 2) * 64 : 0;   // wrap: harmless prefetch

        const int aB = sl + aoff;
        const int bB = sl + boff;
        short8 a00 = *(const short8*)&lds[aB + sk0 +    0];
        short8 a10 = *(const short8*)&lds[aB + sk0 + 1024];
        short8 a20 = *(const short8*)&lds[aB + sk0 + 2048];
        short8 a30 = *(const short8*)&lds[aB + sk0 + 3072];
        short8 b00 = *(const short8*)&lds[bB + sk0 +    0];
        short8 b10 = *(const short8*)&lds[bB + sk0 + 1024];
        short8 b20 = *(const short8*)&lds[bB + sk0 + 2048];
        short8 b30 = *(const short8*)&lds[bB + sk0 + 3072];
        short8 a01 = *(const short8*)&lds[aB + sk1 +    0];
        short8 a11 = *(const short8*)&lds[aB + sk1 + 1024];
        short8 a21 = *(const short8*)&lds[aB + sk1 + 2048];
        short8 a31 = *(const short8*)&lds[aB + sk1 + 3072];
        short8 b01 = *(const short8*)&lds[bB + sk1 +    0];
        short8 b11 = *(const short8*)&lds[bB + sk1 + 1024];
        short8 b21 = *(const short8*)&lds[bB + sk1 + 2048];
        short8 b31 = *(const short8*)&lds[bB + sk1 + 3072];

        STGA(nkb, nsl);
        STGB(nkb, nsl);
        asm volatile("s_waitcnt vmcnt(6)" ::: "memory");
        __builtin_amdgcn_s_barrier();

        __builtin_amdgcn_s_setprio(1);
        acc[0][0] = __builtin_amdgcn_mfma_f32_16x16x32_bf16(a00, b00, acc[0][0], 0, 0, 0);
        acc[0][1] = __builtin_amdgcn_mfma_f32_16x16x32_bf16(a00, b10, acc[0][1], 0, 0, 0);
        acc[0][2] = __builtin_amdgcn_mfma_f32_16x16x32_bf16(a00, b20, acc[0][2], 0, 0, 0);
        acc[0][3] = __builtin_amdgcn_mfma_f32_16x16x32_bf16(a00, b30, acc[0][3], 0, 0, 0);
        acc[1][0] = __builtin_amdgcn_mfma_f32_16x16x32_bf16(a10, b00, acc[1][0], 0, 0, 0);
        acc[1][1] = __builtin_amdgcn_mfma_f32_16x16x32_bf16(a10, b10, acc[1][1], 0, 0, 0);
        acc[1][2] = __builtin_amdgcn_mfma_f32_16x16x32_bf16(a10, b20, acc[1][2], 0, 0, 0);
        acc[1][3] = __builtin_amdgcn_mfma_f32_16x16x32_bf16(a10, b30, acc[1][3], 0, 0, 0);
        acc[2][0] = __builtin_amdgcn_mfma_f32_16x16x32_bf16(a20, b00, acc[2][0], 0, 0, 0);
        acc[2][1] = __builtin_amdgcn_mfma_f32_16x16x32_bf16(a20, b10, acc[2][1], 0, 0, 0);
        acc[2][2] = __builtin_amdgcn_mfma_f32_16x16x32_bf16(a20, b20, acc[2][2], 0, 0, 0);
        acc[2][3] = __builtin_amdgcn_mfma_f32_16x16x32_bf16(a20, b30, acc[2][3], 0, 0, 0);
        acc[3][0] = __builtin_amdgcn_mfma_f32_16x16x32_bf16(a30, b00, acc[3][0], 0, 0, 0);
        acc[3][1] = __builtin_amdgcn_mfma_f32_16x16x32_bf16(a30, b10, acc[3][1], 0, 0, 0);
        acc[3][2] = __builtin_amdgcn_mfma_f32_16x16x32_bf16(a30, b20, acc[3][2], 0, 0, 0);
        acc[3][3] = __builtin_amdgcn_mfma_f32_16x16x32_bf16(a30, b30, acc[3][3], 0, 0, 0);
        acc[0][0] = __builtin_amdgcn_mfma_f32_16x16x32_bf16(a01, b01, acc[0][0], 0, 0, 0);
        acc[0][1] = __builtin_amdgcn_mfma_f32_16x16x32_bf16(a01, b11, acc[0][1], 0, 0, 0);
        acc[0][2] = __builtin_amdgcn_mfma_f32_16x16x32_bf16(a01, b21, acc[0][2], 0, 0, 0);
        acc[0][3] = __builtin_amdgcn_mfma_f32_16x16x32_bf16(a01, b31, acc[0][3], 0, 0, 0);
        acc[1][0] = __builtin_amdgcn_mfma_f32_16x16x32_bf16(a11, b01, acc[1][0], 0, 0, 0);
        acc[1][1] = __builtin_amdgcn_mfma_f32_16x16x32_bf16(a11, b11, acc[1][1], 0, 0, 0);
        acc[1][2] = __builtin_amdgcn_mfma_f32_16x16x32_bf16(a11, b21, acc[1][2], 0, 0, 0);
        acc[1][3] = __builtin_amdgcn_mfma_f32_16x16x32_bf16(a11, b31, acc[1][3], 0, 0, 0);
        acc[2][0] = __builtin_amdgcn_mfma_f32_16x16x32_bf16(a21, b01, acc[2][0], 0, 0, 0);
        acc[2][1] = __builtin_amdgcn_mfma_f32_16x16x32_bf16(a21, b11, acc[2][1], 0, 0, 0);
        acc[2][2] = __builtin_amdgcn_mfma_f32_16x16x32_bf16(a21, b21, acc[2][2], 0, 0, 0);
        acc[2][3] = __builtin_amdgcn_mfma_f32_16x16x32_bf16(a21, b31, acc[2][3], 0, 0, 0);
        acc[3][0] = __builtin_amdgcn_mfma_f32_16x16x32_bf16(a31, b01, acc[3][0], 0, 0, 0);
        acc[3][1] = __builtin_amdgcn_mfma_f32_16x16x32_bf16(a31, b11, acc[3][1], 0, 0, 0);
        acc[3][2] = __builtin_amdgcn_mfma_f32_16x16x32_bf16(a31, b21, acc[3][2], 0, 0, 0);
        acc[3][3] = __builtin_amdgcn_mfma_f32_16x16x32_bf16(a31, b31, acc[3][3], 0, 0, 0);
        __builtin_amdgcn_s_setprio(0);
    }
#undef STGA
#undef STGB

    // epilogue (unswapped): row = m0 + wr*64 + i*16 + q*4 + rr, col = n0 + wc*64 + j*16 + r
    const int gmb = m0 + wr * 64 + q * 4;
    const int gnb = n0 + wc * 64 + r;
    if (nt < 8) {
#pragma unroll
        for (int i = 0; i < 4; i++) {
            const int gm = gmb + i * 16;
#pragma unroll
            for (int j = 0; j < 4; j++) {
                const int gn = gnb + j * 16;
#pragma unroll
                for (int rr = 0; rr < 4; rr++)
                    Qo[(size_t)(gm + rr) * 1024 + gn] = f2b(acc[i][j][rr] * qscale);
            }
        }
    } else if (nt < 16) {
#pragma unroll
        for (int i = 0; i < 4; i++) {
            const int gm = gmb + i * 16;
#pragma unroll
            for (int j = 0; j < 4; j++) {
                const int gn = gnb + j * 16;
#pragma unroll
                for (int rr = 0; rr < 4; rr++)
                    Ko[(size_t)(gm + rr) * 1024 + (gn - 1024)] = f2b(acc[i][j][rr]);
            }
        }
    } else {
#pragma unroll
        for (int i = 0; i < 4; i++) {
            const int gm = gmb + i * 16;
            const int b  = gm >> 11;
            const int s  = gm & 2047;          // 4 consecutive tokens via rr
#pragma unroll
            for (int j = 0; j < 4; j++) {
                const int v = gnb + j * 16 - 2048;
                *(ushort4*)&Vto[((size_t)(b * 1024 + v)) * 2048 + s] =
                    pack4(acc[i][j][0], acc[i][j][1], acc[i][j][2], acc[i][j][3]);
            }
        }
    }
}

// ---------------------------------------------------------------------------
// Attention GEMMs: same BM=256/BN=128/BK=64 structure with the R5 one-barrier
// merged-kk K-loop. MFMA operand order SWAPPED (mfma(bf,af)) -> per-thread
// layout row gm = m0 + wr*64 + i*16 + r, col gn = n0 + wc*64 + j*16 + q*4+rr
// -> 4 consecutive cols per acc: ushort4/float4 stores, 2-shfl rowsum reduce.
// MODE 0 (scores): lower-tri 256x128 tiles; E = exp(s) causal (bf16) +
//   rowsum atomics; kEnd = 1024. MODE 1 (PV): C = E*Vt^T / rowsum;
//   kEnd = m0+256, heavy m-tiles first.
// ---------------------------------------------------------------------------
template<int MODE>
__global__ __launch_bounds__(512, 2) void attn256(
    const unsigned short* __restrict__ Ag, const unsigned short* __restrict__ Bg,
    void* __restrict__ Cv, float* __restrict__ rowsum)
{
    __shared__ __align__(16) unsigned short lds[3 * SLOTS];   // 144 KB

    const int z = blockIdx.z;
    int m0, n0;
    if (MODE == 0) {
        // f = ti*(ti+1) + tj, tj in [0, 2ti+2)  (lower-tri tiles of 8 x 16 grid)
        const int f = blockIdx.x;
        int ti = (int)((sqrtf(4.f * f + 1.f) - 1.f) * 0.5f);
        while ((ti + 1) * (ti + 2) <= f) ti++;
        while (ti * (ti + 1) > f) ti--;
        const int tj = f - ti * (ti + 1);
        m0 = ti * 256;
        n0 = tj * 128;
    } else {
        m0 = (int)(gridDim.y - 1 - blockIdx.y) * 256;   // heavy (large kEnd) first
        n0 = blockIdx.x * 128;
    }

    const size_t LDA = (MODE == 0) ? DM : SEQ;
    const size_t LDB = (MODE == 0) ? DM : SEQ;
    const unsigned short* A  = Ag + (size_t)z * ((MODE == 0) ? SEQ * DM : SEQ * SEQ);
    const unsigned short* Bm = Bg + (size_t)z * ((MODE == 0) ? SEQ * DM : DM * SEQ);
    const int NT = ((MODE == 0) ? DM : (m0 + 256)) / 64;   // K-tiles (>= 4)

    const int t    = threadIdx.x;
    const int w    = t >> 6;
    const int lane = t & 63;
    const int wr   = w >> 1, wc = w & 1;
    const int r    = lane & 15, q = lane >> 4;

    const int srow = lane >> 3;
    const int scol = ((lane & 7) ^ srow) << 3;

    const int aoff = (wr >> 1) * 8192 + ((wr & 1) * 64 + r) * 64;
    const int boff = 16384 + (wc * 64 + r) * 64;
    const int sk0  = ((0 + q) ^ (r & 7)) * 8;
    const int sk1  = ((4 + q) ^ (r & 7)) * 8;

    floatx4 acc[4][4];
#pragma unroll
    for (int i = 0; i < 4; i++)
#pragma unroll
        for (int j = 0; j < 4; j++)
            acc[i][j] = (floatx4){0.f, 0.f, 0.f, 0.f};

#define ASTG(KB, SL) do { \
    gload16(A + (size_t)(m0 +       w * 16 + srow) * LDA + (KB) + scol, &lds[(SL) +         w * 1024]); \
    gload16(A + (size_t)(m0 +   8 + w * 16 + srow) * LDA + (KB) + scol, &lds[(SL) +         w * 1024 + 512]); \
    gload16(A + (size_t)(m0 + 128 + w * 16 + srow) * LDA + (KB) + scol, &lds[(SL) + 8192 +  w * 1024]); \
    gload16(A + (size_t)(m0 + 136 + w * 16 + srow) * LDA + (KB) + scol, &lds[(SL) + 8192 +  w * 1024 + 512]); \
  } while (0)
#define BSTG(KB, SL) do { \
    gload16(Bm + (size_t)(n0 +      w * 16 + srow) * LDB + (KB) + scol, &lds[(SL) + 16384 + w * 1024]); \
    gload16(Bm + (size_t)(n0 +  8 + w * 16 + srow) * LDB + (KB) + scol, &lds[(SL) + 16384 + w * 1024 + 512]); \
  } while (0)

    ASTG(0, 0);
    BSTG(0, 0);
    ASTG(64, SLOTS);
    BSTG(64, SLOTS);
    asm volatile("s_waitcnt vmcnt(6)" ::: "memory");
    __builtin_amdgcn_s_barrier();

    for (int tt = 0; tt < NT; ++tt) {
        const int sl  = (tt % 3) * SLOTS;
        const int nsl = ((tt + 2) % 3) * SLOTS;
        const int nkb = (tt + 2 < NT) ? (tt + 2) * 64 : 0;   // wrap: harmless prefetch

        const int aB = sl + aoff;
        const int bB = sl + boff;
        short8 a00 = *(const short8*)&lds[aB + sk0 +    0];
        short8 a10 = *(const short8*)&lds[aB + sk0 + 1024];
        short8 a20 = *(const short8*)&lds[aB + sk0 + 2048];
        short8 a30 = *(const short8*)&lds[aB + sk0 + 3072];
        short8 b00 = *(const short8*)&lds[bB + sk0 +    0];
        short8 b10 = *(const short8*)&lds[bB + sk0 + 1024];
        short8 b20 = *(const short8*)&lds[bB + sk0 + 2048];
        short8 b30 = *(const short8*)&lds[bB + sk0 + 3072];
        short8 a01 = *(const short8*)&lds[aB + sk1 +    0];
        short8 a11 = *(const short8*)&lds[aB + sk1 + 1024];
        short8 a21 = *(const short8*)&lds[aB + sk1 + 2048];
        short8 a31 = *(const short8*)&lds[aB + sk1 + 3072];
        short8 b01 = *(const short8*)&lds[bB + sk1 +    0];
        short8 b11 = *(const short8*)&lds[bB + sk1 + 1024];
        short8 b21 = *(const short8*)&lds[bB + sk1 + 2048];
        short8 b31 = *(const short8*)&lds[bB + sk1 + 3072];

        ASTG(nkb, nsl);
        BSTG(nkb, nsl);
        asm volatile("s_waitcnt vmcnt(6)" ::: "memory");
        __builtin_amdgcn_s_barrier();

        __builtin_amdgcn_s_setprio(1);
        acc[0][0] = __builtin_amdgcn_mfma_f32_16x16x32_bf16(b00, a00, acc[0][0], 0, 0, 0);
        acc[0][1] = __builtin_amdgcn_mfma_f32_16x16x32_bf16(b10, a00, acc[0][1], 0, 0, 0);
        acc[0][2] = __builtin_amdgcn_mfma_f32_16x16x32_bf16(b20, a00, acc[0][2], 0, 0, 0);
        acc[0][3] = __builtin_amdgcn_mfma_f32_16x16x32_bf16(b30, a00, acc[0][3], 0, 0, 0);
        acc[1][0] = __builtin_amdgcn_mfma_f32_16x16x32_bf16(b00, a10, acc[1][0], 0, 0, 0);
        acc[1][1] = __builtin_amdgcn_mfma_f32_16x16x32_bf16(b10, a10, acc[1][1], 0, 0, 0);
        acc[1][2] = __builtin_amdgcn_mfma_f32_16x16x32_bf16(b20, a10, acc[1][2], 0, 0, 0);
        acc[1][3] = __builtin_amdgcn_mfma_f32_16x16x32_bf16(b30, a10, acc[1][3], 0, 0, 0);
        acc[2][0] = __builtin_amdgcn_mfma_f32_16x16x32_bf16(b00, a20, acc[2][0], 0, 0, 0);
        acc[2][1] = __builtin_amdgcn_mfma_f32_16x16x32_bf16(b10, a20, acc[2][1], 0, 0, 0);
        acc[2][2] = __builtin_amdgcn_mfma_f32_16x16x32_bf16(b20, a20, acc[2][2], 0, 0, 0);
        acc[2][3] = __builtin_amdgcn_mfma_f32_16x16x32_bf16(b30, a20, acc[2][3], 0, 0, 0);
        acc[3][0] = __builtin_amdgcn_mfma_f32_16x16x32_bf16(b00, a30, acc[3][0], 0, 0, 0);
        acc[3][1] = __builtin_amdgcn_mfma_f32_16x16x32_bf16(b10, a30, acc[3][1], 0, 0, 0);
        acc[3][2] = __builtin_amdgcn_mfma_f32_16x16x32_bf16(b20, a30, acc[3][2], 0, 0, 0);
        acc[3][3] = __builtin_amdgcn_mfma_f32_16x16x32_bf16(b30, a30, acc[3][3], 0, 0, 0);
        acc[0][0] = __builtin_amdgcn_mfma_f32_16x16x32_bf16(b01, a01, acc[0][0], 0, 0, 0);
        acc[0][1] = __builtin_amdgcn_mfma_f32_16x16x32_bf16(b11, a01, acc[0][1], 0, 0, 0);
        acc[0][2] = __builtin_amdgcn_mfma_f32_16x16x32_bf16(b21, a01, acc[0][2], 0, 0, 0);
        acc[0][3] = __builtin_amdgcn_mfma_f32_16x16x32_bf16(b31, a01, acc[0][3], 0, 0, 0);
        acc[1][0] = __builtin_amdgcn_mfma_f32_16x16x32_bf16(b01, a11, acc[1][0], 0, 0, 0);
        acc[1][1] = __builtin_amdgcn_mfma_f32_16x16x32_bf16(b11, a11, acc[1][1], 0, 0, 0);
        acc[1][2] = __builtin_amdgcn_mfma_f32_16x16x32_bf16(b21, a11, acc[1][2], 0, 0, 0);
        acc[1][3] = __builtin_amdgcn_mfma_f32_16x16x32_bf16(b31, a11, acc[1][3], 0, 0, 0);
        acc[2][0] = __builtin_amdgcn_mfma_f32_16x16x32_bf16(b01, a21, acc[2][0], 0, 0, 0);
        acc[2][1] = __builtin_amdgcn_mfma_f32_16x16x32_bf16(b11, a21, acc[2][1], 0, 0, 0);
        acc[2][2] = __builtin_amdgcn_mfma_f32_16x16x32_bf16(b21, a21, acc[2][2], 0, 0, 0);
        acc[2][3] = __builtin_amdgcn_mfma_f32_16x16x32_bf16(b31, a21, acc[2][3], 0, 0, 0);
        acc[3][0] = __builtin_amdgcn_mfma_f32_16x16x32_bf16(b01, a31, acc[3][0], 0, 0, 0);
        acc[3][1] = __builtin_amdgcn_mfma_f32_16x16x32_bf16(b11, a31, acc[3][1], 0, 0, 0);
        acc[3][2] = __builtin_amdgcn_mfma_f32_16x16x32_bf16(b21, a31, acc[3][2], 0, 0, 0);
        acc[3][3] = __builtin_amdgcn_mfma_f32_16x16x32_bf16(b31, a31, acc[3][3], 0, 0, 0);
        __builtin_amdgcn_s_setprio(0);
    }
#undef ASTG
#undef BSTG

    // swapped epilogue: row gm = m0 + wr*64 + i*16 + r, col gn = n0 + wc*64 + j*16 + q*4 + rr
    const int gmb = m0 + wr * 64 + r;
    const int gnb = n0 + wc * 64 + q * 4;
    if (MODE == 0) {
        unsigned short* E = (unsigned short*)Cv + (size_t)z * SEQ * SEQ;
        float* rs = rowsum + (size_t)z * SEQ;
#pragma unroll
        for (int i = 0; i < 4; i++) {
            const int gm = gmb + i * 16;
            float part = 0.f;
#pragma unroll
            for (int j = 0; j < 4; j++) {
                const int gn = gnb + j * 16;
                float e0 = (gn + 0 <= gm) ? __expf(acc[i][j][0]) : 0.f;
                float e1 = (gn + 1 <= gm) ? __expf(acc[i][j][1]) : 0.f;
                float e2 = (gn + 2 <= gm) ? __expf(acc[i][j][2]) : 0.f;
                float e3 = (gn + 3 <= gm) ? __expf(acc[i][j][3]) : 0.f;
                part += (e0 + e1) + (e2 + e3);
                *(ushort4*)&E[(size_t)gm * SEQ + gn] = pack4(e0, e1, e2, e3);
            }
            // the 4 lanes sharing row gm differ only in q (lane bits 4-5)
            part += __shfl_xor(part, 16, 64);
            part += __shfl_xor(part, 32, 64);
            if (q == 0) atomicAdd(&rs[gm], part);
        }
    } else {
        float* C = (float*)Cv + (size_t)z * SEQ * DM;
        const float* rs = rowsum + (size_t)z * SEQ;
#pragma unroll
        for (int i = 0; i < 4; i++) {
            const int gm = gmb + i * 16;
            const float inv = 1.0f / rs[gm];
#pragma unroll
            for (int j = 0; j < 4; j++) {
                const int gn = gnb + j * 16;
                float4 o;
                o.x = acc[i][j][0] * inv;
                o.y = acc[i][j][1] * inv;
                o.z = acc[i][j][2] * inv;
                o.w = acc[i][j][3] * inv;
                *(float4*)&C[(size_t)gm * DM + gn] = o;
            }
        }
    }
}

extern "C" void kernel_launch(void* const* d_in, const int* in_sizes, int n_in,
                              void* d_out, int out_size, void* d_ws, size_t ws_size,
                              hipStream_t stream) {
    (void)in_sizes; (void)n_in; (void)out_size; (void)ws_size;
    const float* x  = (const float*)d_in[0];
    // d_in[1] = mask (causal; implicit — unused)
    const float* Wq = (const float*)d_in[2];
    const float* Wk = (const float*)d_in[3];
    const float* Wv = (const float*)d_in[4];

    char* base = (char*)d_ws;
    size_t off = 0;
    auto alloc = [&](size_t n) { char* p = base + off; off += (n + 255) & ~(size_t)255; return p; };

    unsigned short* xb   = (unsigned short*)alloc((size_t)NBAT * SEQ * DM * 2);  // 16.8 MB
    unsigned short* wall = (unsigned short*)alloc((size_t)3 * DM * DM * 2);      // 6.3 MB
    unsigned short* Qb   = (unsigned short*)alloc((size_t)NBAT * SEQ * DM * 2);  // scaled 1/32
    unsigned short* Kb   = (unsigned short*)alloc((size_t)NBAT * SEQ * DM * 2);
    unsigned short* Vtb  = (unsigned short*)alloc((size_t)NBAT * DM * SEQ * 2);  // [b][v][s]
    unsigned short* E    = (unsigned short*)alloc((size_t)NBAT * SEQ * SEQ * 2); // 33.5 MB
    float*          rsum = (float*)alloc((size_t)NBAT * SEQ * 4);

    // 1) fused prep: x cast + weight casts + rowsum zero (one dispatch, 11296 blocks)
    prep<<<dim3(11296), dim3(256), 0, stream>>>(
        (const float4*)x, (const float4*)Wq, (const float4*)Wk, (const float4*)Wv,
        (ushort4*)xb, (ushort4*)wall, rsum);

    // 2) fused QKV projection: 256x128 tiles, BK=64, 3-slot ring, counted vmcnt;
    //    32x24 = 768 blocks = 3 exact rounds; 1/sqrt(d_k) folded into Q epilogue.
    qkv_gemm<<<dim3(768), dim3(512), 0, stream>>>(
        xb, wall, Qb, Kb, Vtb, 0.03125f);

    // 3) E = exp(Q K^T) causal (bf16) + rowsum; 72 tri-tiles/batch x 4 = 288 blocks
    attn256<0><<<dim3(72, 1, NBAT), dim3(512), 0, stream>>>(Qb, Kb, E, rsum);

    // 4) out = (E Vt^T)/rowsum; 8x8x4 = 256 blocks, heavy m-tiles first
    attn256<1><<<dim3(DM / 128, SEQ / 256, NBAT), dim3(512), 0, stream>>>(E, Vtb, d_out, rsum);
}